// Round 8
// baseline (139.270 us; speedup 1.0000x reference)
//
#include <hip/hip_runtime.h>

// Problem constants
#define HGT 256
#define WID 256
#define CH  64
#define NB  2
#define HW  (HGT * WID)
#define NEG_SLOPE 0.2f

// Tile geometry: each block owns an 8x32 interior, computes feat for the
// 10x34 halo tile into LDS, then aggregates interior from LDS only.
#define TR 8
#define TC 32
#define HR (TR + 2)      // 10 rows with halo
#define HC (TC + 2)      // 34 cols with halo
#define NN (HR * HC)     // 340 halo nodes
#define NG ((NN + 31) / 32)  // 11 MFMA node-groups

typedef float f32x16 __attribute__((ext_vector_type(16)));
typedef short short8 __attribute__((ext_vector_type(8)));

__device__ __forceinline__ unsigned short f2bf(float f) {
    union { float f; unsigned u; } v; v.f = f;
    unsigned r = v.u + 0x7FFF + ((v.u >> 16) & 1);   // RNE
    return (unsigned short)(r >> 16);
}

// ---------------------------------------------------------------------------
// Prep (1 block, R5-proven verbatim): W0/W1/Bc rank-2 pe params
// (pe@lin_w = py*W0 + px*W1 + Bc) and bf16 W^T [co][ci] (8 KB) into ws.
// ---------------------------------------------------------------------------
__global__ __launch_bounds__(256) void gat_prep(
    const float* __restrict__ lin_w, const float* __restrict__ pos_w,
    const float* __restrict__ pos_b,
    float* __restrict__ W0, float* __restrict__ W1, float* __restrict__ Bc,
    unsigned short* __restrict__ wt)
{
    __shared__ float r0[4][64], r1[4][64], r2[4][64];
    const int tid = threadIdx.x;
    const int co  = tid & 63;
    const int ty  = tid >> 6;

    float w0 = 0.f, w1 = 0.f, bc = 0.f;
    #pragma unroll
    for (int p = 0; p < 16; ++p) {
        const int ci = ty * 16 + p;
        const float lwv = lin_w[ci * CH + co];        // coalesced over co
        w0 = fmaf(pos_w[ci],      lwv, w0);
        w1 = fmaf(pos_w[CH + ci], lwv, w1);
        bc = fmaf(pos_b[ci],      lwv, bc);
    }
    r0[ty][co] = w0; r1[ty][co] = w1; r2[ty][co] = bc;

    {
        const int pco = tid >> 2;
        const int cib = (tid & 3) * 16;
        unsigned u[8];
        #pragma unroll
        for (int e = 0; e < 16; e += 2) {
            const unsigned lo = f2bf(lin_w[(cib + e)     * CH + pco]);
            const unsigned hh = f2bf(lin_w[(cib + e + 1) * CH + pco]);
            u[e >> 1] = lo | (hh << 16);
        }
        uint4* dst = (uint4*)(wt + pco * CH + cib);
        dst[0] = make_uint4(u[0], u[1], u[2], u[3]);
        dst[1] = make_uint4(u[4], u[5], u[6], u[7]);
    }

    __syncthreads();
    if (ty == 0) {
        W0[co] = r0[0][co] + r0[1][co] + r0[2][co] + r0[3][co];
        W1[co] = r1[0][co] + r1[1][co] + r1[2][co] + r1[3][co];
        Bc[co] = r2[0][co] + r2[1][co] + r2[2][co] + r2[3][co];
    }
}

// ---------------------------------------------------------------------------
// Fused tile kernel (ordinary launch, no grid sync needed):
// Phase 1: feat for the 10x34 halo tile via mfma_f32_32x32x16_bf16 (weights
//   from global wt, R5-proven fragment path); hfeat quads + asrc/adst -> LDS.
// Phase 2: per interior pixel, softmax over <=9 valid taps + weighted sum,
//   everything read from LDS (stride-8B lane pattern = 2-way = free).
// Grid 512 = 2 b x 32 rb x 8 cb, bijective XCD swizzle (8 x 64).
// ---------------------------------------------------------------------------
__global__ __launch_bounds__(256) void gat_fused(
    const float* __restrict__ x, const float* __restrict__ att_src,
    const float* __restrict__ att_dst, const float* __restrict__ W0g,
    const float* __restrict__ W1g, const float* __restrict__ Bcg,
    const unsigned short* __restrict__ wt, const float* __restrict__ bias,
    float* __restrict__ outp)
{
    __shared__ uint2 hlds[16 * NN];          // 43520 B: [q][node] channel-quads
    __shared__ float aslds[NN], adlds[NN];   // 2720 B

    const int tid  = threadIdx.x;
    const int lane = tid & 63;
    const int wid  = tid >> 6;        // wave 0..3
    const int hi   = lane >> 5;
    const int col  = lane & 31;

    const int blk  = blockIdx.x;
    const int sblk = (blk & 7) * 64 + (blk >> 3);   // bijective: 512 = 8*64
    const int b    = sblk >> 8;                     // batch
    const int tix  = sblk & 255;
    const int i0   = (tix >> 3) * TR;               // tile origin
    const int j0   = (tix & 7) * TC;

    // ---- A-fragments (weights) from global wt (R5-proven): ci = 16ks+8hi+e
    short8 a0[4], a1[4];
    #pragma unroll
    for (int ks = 0; ks < 4; ++ks) {
        a0[ks] = *(const short8*)(wt + col * CH        + ks * 16 + hi * 8);
        a1[ks] = *(const short8*)(wt + (32 + col) * CH + ks * 16 + hi * 8);
    }

    // ================= Phase 1: feat for halo nodes =================
    for (int g = wid; g < NG; g += 4) {
        int nd = g * 32 + col;
        if (nd > NN - 1) nd = NN - 1;               // clamp (dup writes same value)
        const int r = nd / HC;
        const int c = nd - r * HC;
        int gi = i0 + r - 1; gi = gi < 0 ? 0 : (gi > HGT - 1 ? HGT - 1 : gi);
        int gj = j0 + c - 1; gj = gj < 0 ? 0 : (gj > WID - 1 ? WID - 1 : gj);

        // B-fragments: x^T[ci][node], 32 independent plane loads
        const float* xp = x + (size_t)b * CH * HW + gi * WID + gj;
        float xv[32];
        #pragma unroll
        for (int ks = 0; ks < 4; ++ks)
            #pragma unroll
            for (int e = 0; e < 8; ++e)
                xv[ks * 8 + e] = xp[(size_t)(16 * ks + 8 * hi + e) * HW];

        f32x16 acc0, acc1;
        #pragma unroll
        for (int k = 0; k < 16; ++k) { acc0[k] = 0.f; acc1[k] = 0.f; }

        #pragma unroll
        for (int ks = 0; ks < 4; ++ks) {
            short8 bk;
            #pragma unroll
            for (int e = 0; e < 8; ++e)
                bk[e] = (short)f2bf(xv[ks * 8 + e]);
            acc0 = __builtin_amdgcn_mfma_f32_32x32x16_bf16(a0[ks], bk, acc0, 0, 0, 0);
            acc1 = __builtin_amdgcn_mfma_f32_32x32x16_bf16(a1[ks], bk, acc1, 0, 0, 0);
        }

        // epilogue (R5-proven math): pe correction, att dots, pack quads -> LDS
        const float py = -1.f + (2.f / 255.f) * (float)gi;
        const float px = -1.f + (2.f / 255.f) * (float)gj;
        float as = 0.f, ad = 0.f;

        #pragma unroll
        for (int t = 0; t < 2; ++t) {
            const f32x16 A = (t == 0) ? acc0 : acc1;
            #pragma unroll
            for (int q2 = 0; q2 < 4; ++q2) {
                const int cb = 32 * t + 8 * q2 + 4 * hi;   // channel-quad base
                const float4 w0 = *(const float4*)&W0g[cb];
                const float4 w1 = *(const float4*)&W1g[cb];
                const float4 bc = *(const float4*)&Bcg[cb];
                const float4 s4 = *(const float4*)&att_src[cb];
                const float4 d4 = *(const float4*)&att_dst[cb];
                const float h0 = A[4 * q2 + 0] + py * w0.x + px * w1.x + bc.x;
                const float h1 = A[4 * q2 + 1] + py * w0.y + px * w1.y + bc.y;
                const float h2 = A[4 * q2 + 2] + py * w0.z + px * w1.z + bc.z;
                const float h3 = A[4 * q2 + 3] + py * w0.w + px * w1.w + bc.w;
                as += h0 * s4.x + h1 * s4.y + h2 * s4.z + h3 * s4.w;
                ad += h0 * d4.x + h1 * d4.y + h2 * d4.z + h3 * d4.w;
                const unsigned u0 = (unsigned)f2bf(h0) | ((unsigned)f2bf(h1) << 16);
                const unsigned u1 = (unsigned)f2bf(h2) | ((unsigned)f2bf(h3) << 16);
                const int q = 8 * t + 2 * q2 + hi;         // quad index = cb/4
                hlds[q * NN + nd] = make_uint2(u0, u1);    // lane stride 8B: free
            }
        }

        as += __shfl_xor(as, 32);
        ad += __shfl_xor(ad, 32);
        if (hi == 0) { aslds[nd] = as; adlds[nd] = ad; }
    }

    __syncthreads();

    // ================= Phase 2: aggr for interior pixels =================
    const int pr = tid >> 5;               // 0..7
    const int pc = tid & 31;               // 0..31
    const int i  = i0 + pr;
    const int j  = j0 + pc;
    const int nd = (pr + 1) * HC + (pc + 1);

    const float adv = adlds[nd];

    float w[9];
    int   tp[9];
    float m = -1e30f;
    #pragma unroll
    for (int t = 0; t < 9; ++t) {
        const int dr = t / 3 - 1, dc = t % 3 - 1;
        const int ri = i + dr, cj = j + dc;
        const bool ok = (ri >= 0) && (ri < HGT) && (cj >= 0) && (cj < WID);
        tp[t] = nd + dr * HC + dc;         // always inside halo tile
        float ev = -1e30f;
        if (ok) {
            ev = aslds[tp[t]] + adv;
            ev = (ev >= 0.f) ? ev : NEG_SLOPE * ev;
        }
        w[t] = ev;
        m = fmaxf(m, ev);
    }

    float s = 0.f;
    #pragma unroll
    for (int t = 0; t < 9; ++t) {
        const float p = (w[t] > -1e29f) ? __expf(w[t] - m) : 0.f;
        w[t] = p; s += p;
    }
    const float inv = 1.f / s;
    #pragma unroll
    for (int t = 0; t < 9; ++t) w[t] *= inv;

    float* ob = outp + (size_t)b * CH * HW + i * WID + j;
    #pragma unroll
    for (int q = 0; q < 16; ++q) {
        float a0v = 0.f, a1v = 0.f, a2v = 0.f, a3v = 0.f;
        #pragma unroll
        for (int t = 0; t < 9; ++t) {
            const uint2 v  = hlds[q * NN + tp[t]];   // lane stride 8B: free
            const float wv = w[t];
            a0v = fmaf(wv, __uint_as_float(v.x << 16),         a0v);
            a1v = fmaf(wv, __uint_as_float(v.x & 0xffff0000u), a1v);
            a2v = fmaf(wv, __uint_as_float(v.y << 16),         a2v);
            a3v = fmaf(wv, __uint_as_float(v.y & 0xffff0000u), a3v);
        }
        ob[(size_t)(4 * q + 0) * HW] = a0v + bias[4 * q + 0];
        ob[(size_t)(4 * q + 1) * HW] = a1v + bias[4 * q + 1];
        ob[(size_t)(4 * q + 2) * HW] = a2v + bias[4 * q + 2];
        ob[(size_t)(4 * q + 3) * HW] = a3v + bias[4 * q + 3];
    }
}

// ---------------------------------------------------------------------------
extern "C" void kernel_launch(void* const* d_in, const int* in_sizes, int n_in,
                              void* d_out, int out_size, void* d_ws, size_t ws_size,
                              hipStream_t stream) {
    const float* x       = (const float*)d_in[0];
    const float* pos_w   = (const float*)d_in[1];
    const float* pos_b   = (const float*)d_in[2];
    const float* lin_w   = (const float*)d_in[3];
    const float* att_src = (const float*)d_in[4];
    const float* att_dst = (const float*)d_in[5];
    const float* bias    = (const float*)d_in[6];
    // edge_src / edge_dst (d_in[7], d_in[8]) are implied by the fixed grid topology.

    float* outp = (float*)d_out;
    float* W0   = (float*)d_ws;                 // 64 f32
    float* W1   = W0 + CH;
    float* Bc   = W1 + CH;
    unsigned short* wt = (unsigned short*)(Bc + CH);   // 64x64 bf16 W^T

    gat_prep<<<dim3(1), dim3(256), 0, stream>>>(lin_w, pos_w, pos_b, W0, W1, Bc, wt);
    gat_fused<<<dim3(512), dim3(256), 0, stream>>>(
        x, att_src, att_dst, W0, W1, Bc, wt, bias, outp);
}

// Round 9
// 128.337 us; speedup vs baseline: 1.0852x; 1.0852x over previous
//
#include <hip/hip_runtime.h>

// Problem constants
#define HGT 256
#define WID 256
#define CH  64
#define NB  2
#define HW  (HGT * WID)
#define NODES (NB * HW)
#define NEG_SLOPE 0.2f

typedef float f32x16 __attribute__((ext_vector_type(16)));
typedef short short8 __attribute__((ext_vector_type(8)));

__device__ __forceinline__ unsigned short f2bf(float f) {
    union { float f; unsigned u; } v; v.f = f;
    unsigned r = v.u + 0x7FFF + ((v.u >> 16) & 1);   // RNE
    return (unsigned short)(r >> 16);
}

// ---------------------------------------------------------------------------
// Prep (1 block): W0/W1/Bc rank-2 pe params (pe@lin_w = py*W0 + px*W1 + Bc)
// and bf16 W^T [co][ci] (8 KB) into workspace.
// ---------------------------------------------------------------------------
__global__ __launch_bounds__(256) void gat_prep(
    const float* __restrict__ lin_w, const float* __restrict__ pos_w,
    const float* __restrict__ pos_b,
    float* __restrict__ W0, float* __restrict__ W1, float* __restrict__ Bc,
    unsigned short* __restrict__ wt)
{
    __shared__ float r0[4][64], r1[4][64], r2[4][64];
    const int tid = threadIdx.x;
    const int co  = tid & 63;
    const int ty  = tid >> 6;

    float w0 = 0.f, w1 = 0.f, bc = 0.f;
    #pragma unroll
    for (int p = 0; p < 16; ++p) {
        const int ci = ty * 16 + p;
        const float lwv = lin_w[ci * CH + co];        // coalesced over co
        w0 = fmaf(pos_w[ci],      lwv, w0);
        w1 = fmaf(pos_w[CH + ci], lwv, w1);
        bc = fmaf(pos_b[ci],      lwv, bc);
    }
    r0[ty][co] = w0; r1[ty][co] = w1; r2[ty][co] = bc;

    {
        const int pco = tid >> 2;
        const int cib = (tid & 3) * 16;
        unsigned u[8];
        #pragma unroll
        for (int e = 0; e < 16; e += 2) {
            const unsigned lo = f2bf(lin_w[(cib + e)     * CH + pco]);
            const unsigned hh = f2bf(lin_w[(cib + e + 1) * CH + pco]);
            u[e >> 1] = lo | (hh << 16);
        }
        uint4* dst = (uint4*)(wt + pco * CH + cib);
        dst[0] = make_uint4(u[0], u[1], u[2], u[3]);
        dst[1] = make_uint4(u[4], u[5], u[6], u[7]);
    }

    __syncthreads();
    if (ty == 0) {
        W0[co] = r0[0][co] + r0[1][co] + r0[2][co] + r0[3][co];
        W1[co] = r1[0][co] + r1[1][co] + r1[2][co] + r1[3][co];
        Bc[co] = r2[0][co] + r2[1][co] + r2[2][co] + r2[3][co];
    }
}

// ---------------------------------------------------------------------------
// Kernel A (MFMA, barrier-free, LDS-free): hfeat^T = W^T @ x^T in bf16.
// Block = 256 thr = 4 waves, grid 1024; each wave owns one 32-node group.
// launch_bounds(256,4): cap VGPR at 128 -> 4 blocks/CU resident (16 waves/CU,
// perfectly balanced 1024 = 4x256). True live state ~104 VGPR, so no spill.
// A-fragments read directly from the 8 KB global W^T (L2-resident).
// MFMA v_mfma_f32_32x32x16_bf16: D col=lane&31 (node),
// row=(reg&3)+8*(reg>>2)+4*(lane>>5); A row=lane&31 (co), k=(lane>>5)*8+e.
// ---------------------------------------------------------------------------
__global__ __launch_bounds__(256, 4) void gat_feat(
    const float* __restrict__ x, const float* __restrict__ att_src,
    const float* __restrict__ att_dst, const float* __restrict__ W0s,
    const float* __restrict__ W1s, const float* __restrict__ Bcs,
    const unsigned short* __restrict__ wt,
    unsigned short* __restrict__ hfeat, float* __restrict__ asrc,
    float* __restrict__ adst)
{
    const int tid  = threadIdx.x;
    const int lane = tid & 63;
    const int wid  = tid >> 6;        // wave 0..3
    const int hi   = lane >> 5;
    const int col  = lane & 31;

    // ---- this wave's 32-node group
    const int g     = blockIdx.x * 4 + wid;       // 0..4095
    const int node0 = g * 32;
    const int b     = node0 >> 16;
    const int hw    = (node0 & (HW - 1)) + col;
    const int node  = node0 + col;

    // ---- B-fragments first: x^T[ci][node], 32 independent plane loads
    const float* xp = x + (size_t)b * CH * HW + hw;
    float xv[32];
    #pragma unroll
    for (int ks = 0; ks < 4; ++ks)
        #pragma unroll
        for (int e = 0; e < 8; ++e)
            xv[ks * 8 + e] = xp[(size_t)(16 * ks + 8 * hi + e) * HW];

    // ---- A-fragments (weights) straight from global: ci = 16*ks + 8*hi + e
    short8 a0[4], a1[4];
    #pragma unroll
    for (int ks = 0; ks < 4; ++ks) {
        a0[ks] = *(const short8*)(wt + col * CH        + ks * 16 + hi * 8);
        a1[ks] = *(const short8*)(wt + (32 + col) * CH + ks * 16 + hi * 8);
    }

    f32x16 acc0, acc1;
    #pragma unroll
    for (int k = 0; k < 16; ++k) { acc0[k] = 0.f; acc1[k] = 0.f; }

    #pragma unroll
    for (int ks = 0; ks < 4; ++ks) {
        short8 bk;
        #pragma unroll
        for (int e = 0; e < 8; ++e)
            bk[e] = (short)f2bf(xv[ks * 8 + e]);
        acc0 = __builtin_amdgcn_mfma_f32_32x32x16_bf16(a0[ks], bk, acc0, 0, 0, 0);
        acc1 = __builtin_amdgcn_mfma_f32_32x32x16_bf16(a1[ks], bk, acc1, 0, 0, 0);
    }

    // ---- epilogue: pe correction, att dots, pack bf16 quads
    const int ii = hw >> 8, jj = hw & 255;
    const float py = -1.f + (2.f / 255.f) * (float)ii;
    const float px = -1.f + (2.f / 255.f) * (float)jj;

    uint2* hq = (uint2*)hfeat + (size_t)b * 16 * HW + hw;
    float as = 0.f, ad = 0.f;

    #pragma unroll
    for (int t = 0; t < 2; ++t) {
        const f32x16 A = (t == 0) ? acc0 : acc1;
        #pragma unroll
        for (int q2 = 0; q2 < 4; ++q2) {
            const int cb = 32 * t + 8 * q2 + 4 * hi;   // channel-quad base
            const float4 w0 = *(const float4*)&W0s[cb];
            const float4 w1 = *(const float4*)&W1s[cb];
            const float4 bc = *(const float4*)&Bcs[cb];
            const float4 s4 = *(const float4*)&att_src[cb];
            const float4 d4 = *(const float4*)&att_dst[cb];
            const float h0 = A[4 * q2 + 0] + py * w0.x + px * w1.x + bc.x;
            const float h1 = A[4 * q2 + 1] + py * w0.y + px * w1.y + bc.y;
            const float h2 = A[4 * q2 + 2] + py * w0.z + px * w1.z + bc.z;
            const float h3 = A[4 * q2 + 3] + py * w0.w + px * w1.w + bc.w;
            as += h0 * s4.x + h1 * s4.y + h2 * s4.z + h3 * s4.w;
            ad += h0 * d4.x + h1 * d4.y + h2 * d4.z + h3 * d4.w;
            const unsigned u0 = (unsigned)f2bf(h0) | ((unsigned)f2bf(h1) << 16);
            const unsigned u1 = (unsigned)f2bf(h2) | ((unsigned)f2bf(h3) << 16);
            const int q = 8 * t + 2 * q2 + hi;         // quad index = cb/4
            hq[(size_t)q * HW] = make_uint2(u0, u1);
        }
    }

    as += __shfl_xor(as, 32);
    ad += __shfl_xor(ad, 32);
    if (hi == 0) { asrc[node] = as; adst[node] = ad; }
}

// ---------------------------------------------------------------------------
// Kernel B (R5-proven verbatim): softmax over <=9 taps + weighted sum + bias.
// Thread = (pixel, channel-quad): 9 uint2 loads, 36 FMA. Grid 8192, 32 w/CU,
// bijective XCD swizzle keeps same-pixel-area blocks on one XCD.
// ---------------------------------------------------------------------------
__global__ __launch_bounds__(256) void gat_aggr(
    const unsigned short* __restrict__ hfeat, const float* __restrict__ asrc,
    const float* __restrict__ adst, const float* __restrict__ bias,
    float* __restrict__ out)
{
    const int tid = threadIdx.x;
    const int tx  = tid & 63;
    const int ty  = tid >> 6;

    const int raw = blockIdx.x;                 // 8192 = 8 XCD * 1024 (bijective)
    const int wg  = (raw & 7) * 1024 + (raw >> 3);
    const int qg    = wg & 3;
    const int chunk = (wg >> 2) & 3;
    const int bi    = wg >> 4;                  // b*256 + i
    const int i     = bi & (HGT - 1);
    const int b     = bi >> 8;
    const int j     = chunk * 64 + tx;
    const int hw    = i * WID + j;
    const int node  = b * HW + hw;
    const int q     = __builtin_amdgcn_readfirstlane(qg * 4 + ty);  // quad 0..15

    const float adv = adst[node];

    float w[9];
    int   off[9];
    float m = -1e30f;
    #pragma unroll
    for (int t = 0; t < 9; ++t) {
        const int dr = t / 3 - 1, dc = t % 3 - 1;
        const int r = i + dr, c = j + dc;
        const bool ok = (r >= 0) && (r < HGT) && (c >= 0) && (c < WID);
        off[t] = ok ? (dr * WID + dc) : 0;      // clamped -> in-bounds
        float ev = -1e30f;
        if (ok) {
            ev = asrc[node + off[t]] + adv;
            ev = (ev >= 0.f) ? ev : NEG_SLOPE * ev;
        }
        w[t] = ev;
        m = fmaxf(m, ev);
    }

    float s = 0.f;
    #pragma unroll
    for (int t = 0; t < 9; ++t) {
        const float p = (w[t] > -1e29f) ? __expf(w[t] - m) : 0.f;
        w[t] = p; s += p;
    }
    const float inv = 1.f / s;

    const uint2* hq = (const uint2*)hfeat + (size_t)(b * 16 + q) * HW + hw;

    float a0 = 0.f, a1 = 0.f, a2 = 0.f, a3 = 0.f;
    #pragma unroll
    for (int t = 0; t < 9; ++t) {
        const uint2 v  = hq[off[t]];
        const float wt = w[t] * inv;
        a0 = fmaf(wt, __uint_as_float(v.x << 16),         a0);
        a1 = fmaf(wt, __uint_as_float(v.x & 0xffff0000u), a1);
        a2 = fmaf(wt, __uint_as_float(v.y << 16),         a2);
        a3 = fmaf(wt, __uint_as_float(v.y & 0xffff0000u), a3);
    }

    float* ob = out + (size_t)(b * CH + q * 4) * HW + hw;
    ob[0 * (size_t)HW] = a0 + bias[q * 4 + 0];
    ob[1 * (size_t)HW] = a1 + bias[q * 4 + 1];
    ob[2 * (size_t)HW] = a2 + bias[q * 4 + 2];
    ob[3 * (size_t)HW] = a3 + bias[q * 4 + 3];
}

// ---------------------------------------------------------------------------
extern "C" void kernel_launch(void* const* d_in, const int* in_sizes, int n_in,
                              void* d_out, int out_size, void* d_ws, size_t ws_size,
                              hipStream_t stream) {
    const float* x       = (const float*)d_in[0];
    const float* pos_w   = (const float*)d_in[1];
    const float* pos_b   = (const float*)d_in[2];
    const float* lin_w   = (const float*)d_in[3];
    const float* att_src = (const float*)d_in[4];
    const float* att_dst = (const float*)d_in[5];
    const float* bias    = (const float*)d_in[6];
    // edge_src / edge_dst (d_in[7], d_in[8]) are implied by the fixed grid topology.

    float* out = (float*)d_out;
    char*  ws  = (char*)d_ws;
    unsigned short* hfeat = (unsigned short*)ws;            // NODES*CH bf16, quad-planar
    float* asrc = (float*)(ws + (size_t)NODES * CH * 2);    // NODES f32
    float* adst = asrc + NODES;                             // NODES f32
    float* W0   = adst + NODES;                             // 64 f32
    float* W1   = W0 + CH;
    float* Bc   = W1 + CH;
    unsigned short* wt = (unsigned short*)(Bc + CH);        // 64x64 bf16 W^T

    gat_prep<<<dim3(1), dim3(256), 0, stream>>>(lin_w, pos_w, pos_b, W0, W1, Bc, wt);
    gat_feat<<<dim3(1024), dim3(256), 0, stream>>>(
        x, att_src, att_dst, W0, W1, Bc, wt, hfeat, asrc, adst);
    gat_aggr<<<dim3(8192), dim3(256), 0, stream>>>(
        hfeat, asrc, adst, bias, out);
}